// Round 5
// baseline (12863.010 us; speedup 1.0000x reference)
//
#include <hip/hip_runtime.h>
#include <math.h>

// Problem constants
#define TT 256      // sequence length
#define BB 64       // batch
#define DD 300      // embedding dim
#define KP0 320     // layer-0 K padded to multiple of 32
#define HH 256      // hidden
#define KK 37       // CRF states
#define FH 1024     // 4*H
#define MTOT (TT*BB) // 16384 rows, time-major r = t*64 + b

typedef __attribute__((ext_vector_type(8))) short short8;  // 8 bf16 (4 VGPR) MFMA A/B frag
typedef __attribute__((ext_vector_type(4))) float f32x4;   // MFMA C/D frag

// ---------- bf16 helpers ----------
__device__ __forceinline__ float bf2f(unsigned short u) {
    union { float f; unsigned int i; } v; v.i = ((unsigned int)u) << 16; return v.f;
}
__device__ __forceinline__ unsigned short f2bf(float f) {
    union { float f; unsigned int i; } v; v.f = f;
    unsigned int i = v.i;
    unsigned int r = (i + 0x7FFFu + ((i >> 16) & 1u)) >> 16; // RNE
    return (unsigned short)r;
}
__device__ __forceinline__ float bflo(unsigned int w) {
    union { float f; unsigned int i; } v; v.i = w << 16; return v.f;
}
__device__ __forceinline__ float bfhi(unsigned int w) {
    union { float f; unsigned int i; } v; v.i = w & 0xFFFF0000u; return v.f;
}
__device__ __forceinline__ float sigm(float x)   { return 1.0f / (1.0f + __expf(-x)); }
__device__ __forceinline__ float tanh_f(float x) { return 2.0f / (1.0f + __expf(-2.0f * x)) - 1.0f; }

// permute gate-major col (g*256+unit) -> interleaved (unit*4+g)
__device__ __forceinline__ int perm_col(int nn) { return ((nn & 255) << 2) | (nn >> 8); }

// ---------- prep: WP packed bf16 recurrent weights ----------
// word[((kq*32 + j2)*256 + u)*4 + w4], k = kq*64 + j2*2 + (w4>>1)
// w4&1==0 -> pack(gate_i, gate_f) at k ; w4&1==1 -> pack(gate_g, gate_o)
__global__ __launch_bounds__(256) void conv_whh(
    const float* __restrict__ w0f, const float* __restrict__ w0b,
    const float* __restrict__ w1f, const float* __restrict__ w1b,
    unsigned int* __restrict__ WP)
{
    const int idx = blockIdx.x * 256 + threadIdx.x;
    const int m = idx >> 17;
    const int r = idx & 131071;
    const float* W = m == 0 ? w0f : m == 1 ? w0b : m == 2 ? w1f : w1b;
    const int w4 = r & 3;
    const int u  = (r >> 2) & 255;
    const int j2 = (r >> 10) & 31;
    const int kq = r >> 15;
    const int k  = kq * 64 + j2 * 2 + (w4 >> 1);
    const int g01 = w4 & 1;
    const float f0 = W[((g01 * 2 + 0) * HH + u) * HH + k];
    const float f1 = W[((g01 * 2 + 1) * HH + u) * HH + k];
    WP[idx] = (unsigned int)f2bf(f0) | ((unsigned int)f2bf(f1) << 16);
}

// ---------- prep: WsbjT f32 [512][37] ----------
__global__ __launch_bounds__(256) void conv_wsbj(
    const float* __restrict__ Wsbj, float* __restrict__ WT)
{
    const int idx = blockIdx.x * 256 + threadIdx.x;
    if (idx >= 512 * KK) return;
    const int c = idx / KK, k = idx - c * KK;
    WT[idx] = Wsbj[k * 512 + c];
}

// ---------- prep: gather embedding rows -> Abf bf16 [16384][320] (zero-pad k>=300) ----------
__global__ __launch_bounds__(320) void conv_gather(
    const int* __restrict__ text, const float* __restrict__ emb,
    unsigned short* __restrict__ Abf)
{
    const int r = blockIdx.x;
    const int k = threadIdx.x;
    const int t = r >> 6, b = r & 63;
    const int idx = text[b * TT + t];
    Abf[r * KP0 + k] = (k < DD) ? f2bf(emb[(size_t)idx * DD + k]) : (unsigned short)0;
}

// ---------- prep: W f32 (rows x kin) -> bf16 (rows x kout), zero-pad ----------
__global__ __launch_bounds__(256) void conv_w(
    const float* __restrict__ src, unsigned short* __restrict__ dst,
    int kin, int kout, int total)
{
    const int idx = blockIdx.x * 256 + threadIdx.x;
    if (idx >= total) return;
    const int rr = idx / kout, k = idx - rr * kout;
    dst[idx] = (k < kin) ? f2bf(src[rr * kin + k]) : (unsigned short)0;
}

// ---------- MFMA GEMM: out = A(M x lda bf16) @ W(1024 x lda bf16)^T + bias ----------
// 128x128 tile, 256 threads (4 waves, each 64x64 = 4x4 MFMA_16x16x32_bf16).
// Staging via global_load_lds width=16 (linear LDS layout = lane order, no padding).
// Epilogue: bias add + bf16 + gate-interleave permute store.
__global__ __launch_bounds__(256) void gemm_mfma(
    const unsigned short* __restrict__ A,
    const unsigned short* __restrict__ W,
    const float* __restrict__ bias,
    unsigned short* __restrict__ out,
    int lda)
{
    const int bm = blockIdx.x * 128;
    const int bn = blockIdx.y * 128;
    const int tid = threadIdx.x;
    const int lane = tid & 63;
    const int wave = tid >> 6;
    const int wm = (wave & 1) * 64;
    const int wn = (wave >> 1) * 64;

    __shared__ __align__(16) unsigned short As[128 * 32];  // [row][k] 8 KB
    __shared__ __align__(16) unsigned short Bs[128 * 32];  // [wrow][k] 8 KB

    f32x4 acc[4][4] = {};

    const int srow = tid >> 2;          // 0..63
    const int sk = (tid & 3) * 8;       // k element offset (16 B granules)

    const unsigned short* ga0 = A + (size_t)(bm + srow) * lda + sk;
    const unsigned short* ga1 = A + (size_t)(bm + srow + 64) * lda + sk;
    const unsigned short* gb0 = W + (size_t)(bn + srow) * lda + sk;
    const unsigned short* gb1 = W + (size_t)(bn + srow + 64) * lda + sk;

    unsigned short* lA0 = As + wave * 512;           // byte off = wave*1024 (+lane*16 by HW)
    unsigned short* lA1 = As + 2048 + wave * 512;
    unsigned short* lB0 = Bs + wave * 512;
    unsigned short* lB1 = Bs + 2048 + wave * 512;

    const int kiters = lda >> 5;
    for (int kb = 0; kb < kiters; kb++) {
        const int k0 = kb * 32;
        __builtin_amdgcn_global_load_lds(
            (const __attribute__((address_space(1))) unsigned int*)(ga0 + k0),
            (__attribute__((address_space(3))) unsigned int*)lA0, 16, 0, 0);
        __builtin_amdgcn_global_load_lds(
            (const __attribute__((address_space(1))) unsigned int*)(ga1 + k0),
            (__attribute__((address_space(3))) unsigned int*)lA1, 16, 0, 0);
        __builtin_amdgcn_global_load_lds(
            (const __attribute__((address_space(1))) unsigned int*)(gb0 + k0),
            (__attribute__((address_space(3))) unsigned int*)lB0, 16, 0, 0);
        __builtin_amdgcn_global_load_lds(
            (const __attribute__((address_space(1))) unsigned int*)(gb1 + k0),
            (__attribute__((address_space(3))) unsigned int*)lB1, 16, 0, 0);
        __syncthreads();

        short8 af[4], bfr[4];
        #pragma unroll
        for (int i = 0; i < 4; i++) {
            af[i]  = *(const short8*)&As[(wm + i * 16 + (lane & 15)) * 32 + (lane >> 4) * 8];
            bfr[i] = *(const short8*)&Bs[(wn + i * 16 + (lane & 15)) * 32 + (lane >> 4) * 8];
        }
        #pragma unroll
        for (int i = 0; i < 4; i++)
            #pragma unroll
            for (int j = 0; j < 4; j++)
                acc[i][j] = __builtin_amdgcn_mfma_f32_16x16x32_bf16(af[i], bfr[j], acc[i][j], 0, 0, 0);
        __syncthreads();
    }

    // C/D: col = lane&15, row = (lane>>4)*4 + reg  [measured m89/m91]
    const int cn = lane & 15;
    const int cr = (lane >> 4) * 4;
    #pragma unroll
    for (int j = 0; j < 4; j++) {
        const int n = bn + wn + j * 16 + cn;
        const float bv = bias[n];
        const int pc = perm_col(n);
        #pragma unroll
        for (int i = 0; i < 4; i++) {
            #pragma unroll
            for (int r = 0; r < 4; r++) {
                const int m = bm + wm + i * 16 + cr + r;
                out[(size_t)m * FH + pc] = f2bf(acc[i][j][r] + bv);
            }
        }
    }
}

// ---------- LSTM recurrence: grid (64 batches, 2 dirs), 1024 threads ----------
// tid = kq*256 + u ; kq wave-uniform -> LDS h reads broadcast. Weights streamed
// coalesced uint4 with one-iteration-ahead prefetch (overlap VMEM with FMA).
__global__ __launch_bounds__(1024) void lstm_kernel(
    const unsigned short* __restrict__ zin_f, const unsigned short* __restrict__ zin_b,
    const unsigned int* __restrict__ WPf, const unsigned int* __restrict__ WPb,
    unsigned short* __restrict__ h_out)  // (T,B,512) bf16; fwd cols [0:256), bwd [256:512)
{
    const int dir = blockIdx.y;
    const unsigned short* zin = dir ? zin_b : zin_f;
    const unsigned int*   WP  = dir ? WPb : WPf;
    const int off = dir ? HH : 0;

    const int b = blockIdx.x;
    const int tid = threadIdx.x;
    const int u  = tid & 255;
    const int kq = tid >> 8;

    __shared__ float hs[2][HH];
    __shared__ float4 red[3][HH];
    if (tid < HH) hs[0][tid] = 0.0f;
    float c = 0.0f;
    int cur = 0;

    const uint4* wp = (const uint4*)WP + (kq * 32) * 256 + u;

    __syncthreads();

    for (int ts = 0; ts < TT; ts++) {
        const int tt = dir ? (TT - 1 - ts) : ts;
        const int row = tt * BB + b;

        float ai = 0.f, af = 0.f, ag = 0.f, ao = 0.f;
        uint4 w0 = wp[0];
        uint4 w1 = wp[256];
        #pragma unroll
        for (int j4 = 0; j4 < 16; j4++) {
            uint4 n0, n1;
            if (j4 < 15) {
                n0 = wp[(2 * j4 + 2) * 256];
                n1 = wp[(2 * j4 + 3) * 256];
            } else { n0 = w0; n1 = w1; }
            const float4 hv = *(const float4*)&hs[cur][kq * 64 + j4 * 4];  // broadcast
            ai += bflo(w0.x) * hv.x; af += bfhi(w0.x) * hv.x;
            ag += bflo(w0.y) * hv.x; ao += bfhi(w0.y) * hv.x;
            ai += bflo(w0.z) * hv.y; af += bfhi(w0.z) * hv.y;
            ag += bflo(w0.w) * hv.y; ao += bfhi(w0.w) * hv.y;
            ai += bflo(w1.x) * hv.z; af += bfhi(w1.x) * hv.z;
            ag += bflo(w1.y) * hv.z; ao += bfhi(w1.y) * hv.z;
            ai += bflo(w1.z) * hv.w; af += bfhi(w1.z) * hv.w;
            ag += bflo(w1.w) * hv.w; ao += bfhi(w1.w) * hv.w;
            w0 = n0; w1 = n1;
        }

        if (kq) red[kq - 1][u] = make_float4(ai, af, ag, ao);
        __syncthreads();

        if (kq == 0) {
            const float4 r0 = red[0][u], r1 = red[1][u], r2 = red[2][u];
            const ushort4 zv = *(const ushort4*)(zin + row * FH + 4 * u);
            const float zi  = ai + r0.x + r1.x + r2.x + bf2f(zv.x);
            const float zf_ = af + r0.y + r1.y + r2.y + bf2f(zv.y);
            const float zg  = ag + r0.z + r1.z + r2.z + bf2f(zv.z);
            const float zo  = ao + r0.w + r1.w + r2.w + bf2f(zv.w);
            const float cc = sigm(zf_) * c + sigm(zi) * tanh_f(zg);
            c = cc;
            const float hh = sigm(zo) * tanh_f(cc);
            hs[cur ^ 1][u] = hh;
            h_out[row * (2 * HH) + off + u] = f2bf(hh);
        }
        __syncthreads();
        cur ^= 1;
    }
}

// ---------- Emission: em = h1 @ WsbjT + b_sbj, (MTOT,37) f32 ----------
__global__ __launch_bounds__(256) void em_kernel(
    const unsigned short* __restrict__ h1, const float* __restrict__ WsbjT,
    const float* __restrict__ bsbj, float* __restrict__ em)
{
    const int o = blockIdx.x * 256 + threadIdx.x;
    if (o >= MTOT * KK) return;
    const int r = o / KK, k = o - r * KK;
    const unsigned short* hr = h1 + r * 512;
    float s = bsbj[k];
    #pragma unroll 4
    for (int cidx = 0; cidx < 512; cidx++) {
        s += bf2f(hr[cidx]) * WsbjT[cidx * KK + k];
    }
    em[o] = s;
}

// ---------- CRF: one block (1 wave) per batch ----------
__global__ __launch_bounds__(64) void crf_kernel(
    const int* __restrict__ text, const int* __restrict__ sbj,
    const float* __restrict__ em,
    const float* __restrict__ start_t, const float* __restrict__ end_t,
    const float* __restrict__ trans, float* __restrict__ accum)
{
    const int b = blockIdx.x;
    const int tid = threadIdx.x;
    __shared__ float tr[KK * KK];
    __shared__ float sc[2][KK];
    for (int x = tid; x < KK * KK; x += 64) tr[x] = trans[x];

    int cnt = 0;
    for (int t = tid; t < TT; t += 64) cnt += (text[b * TT + t] != 0) ? 1 : 0;
    #pragma unroll
    for (int s = 32; s > 0; s >>= 1) cnt += __shfl_down(cnt, s, 64);
    const int len = __shfl(cnt, 0, 64);

    __syncthreads();

    float part = 0.f;
    for (int t = tid; t < TT; t += 64) {
        if (t >= 1 && t < len) {
            const int tg = sbj[b * TT + t];
            const int tp = sbj[b * TT + t - 1];
            part += em[(t * BB + b) * KK + tg] + tr[tp * KK + tg];
        }
    }
    #pragma unroll
    for (int s = 32; s > 0; s >>= 1) part += __shfl_down(part, s, 64);

    if (tid < KK) sc[0][tid] = start_t[tid] + em[b * KK + tid];
    __syncthreads();
    int cur = 0;
    for (int t = 1; t < len; t++) {
        float nv = 0.f;
        if (tid < KK) {
            float mx = -1e30f;
            for (int k1 = 0; k1 < KK; k1++)
                mx = fmaxf(mx, sc[cur][k1] + tr[k1 * KK + tid]);
            float s = 0.f;
            for (int k1 = 0; k1 < KK; k1++)
                s += __expf(sc[cur][k1] + tr[k1 * KK + tid] - mx);
            nv = mx + __logf(s) + em[(t * BB + b) * KK + tid];
        }
        if (tid < KK) sc[cur ^ 1][tid] = nv;
        __syncthreads();
        cur ^= 1;
    }

    if (tid == 0) {
        const int tg0 = sbj[b * TT];
        const int tgl = sbj[b * TT + len - 1];
        const float num = start_t[tg0] + em[b * KK + tg0] + part + end_t[tgl];
        float mx = -1e30f;
        for (int k = 0; k < KK; k++) mx = fmaxf(mx, sc[cur][k] + end_t[k]);
        float s = 0.f;
        for (int k = 0; k < KK; k++) s += __expf(sc[cur][k] + end_t[k] - mx);
        const float logZ = mx + __logf(s);
        atomicAdd(&accum[0], num - logZ);
        atomicAdd(&accum[1], (float)len);
    }
}

__global__ void init_kernel(float* __restrict__ accum) {
    if (threadIdx.x < 2) accum[threadIdx.x] = 0.0f;
}
__global__ void final_kernel(const float* __restrict__ accum, float* __restrict__ out) {
    out[0] = -(accum[0] / accum[1]);
}

// ---------- launch ----------
extern "C" void kernel_launch(void* const* d_in, const int* in_sizes, int n_in,
                              void* d_out, int out_size, void* d_ws, size_t ws_size,
                              hipStream_t stream)
{
    (void)in_sizes; (void)n_in; (void)out_size; (void)ws_size;
    const int*   text  = (const int*)d_in[0];
    const int*   sbj   = (const int*)d_in[1];
    const float* emb   = (const float*)d_in[2];
    const float* Wih0f = (const float*)d_in[3];
    const float* Whh0f = (const float*)d_in[4];
    const float* b0f   = (const float*)d_in[5];
    const float* Wih0b = (const float*)d_in[6];
    const float* Whh0b = (const float*)d_in[7];
    const float* b0b   = (const float*)d_in[8];
    const float* Wih1f = (const float*)d_in[9];
    const float* Whh1f = (const float*)d_in[10];
    const float* b1f   = (const float*)d_in[11];
    const float* Wih1b = (const float*)d_in[12];
    const float* Whh1b = (const float*)d_in[13];
    const float* b1b   = (const float*)d_in[14];
    const float* Wsbj  = (const float*)d_in[15];
    const float* bsbj  = (const float*)d_in[16];
    const float* start_t = (const float*)d_in[17];
    const float* end_t   = (const float*)d_in[18];
    const float* trans   = (const float*)d_in[19];

    // workspace map (bytes), max 102.84 MB (same proven budget as rounds 3-4).
    // Overlaps (stream-ordered lifetimes):
    //   Wb0f/Wb0b live in h0 region  (dead before lstm0 writes h0)
    //   Abf, Wb1f/Wb1b live in h1 region (dead before lstm1 writes h1)
    //   em reuses zf (dead after lstm1)
    char* ws = (char*)d_ws;
    unsigned short* zf   = (unsigned short*)(ws + 0);           // 32 MiB
    unsigned short* zb   = (unsigned short*)(ws + 33554432);    // 32 MiB
    unsigned short* h0   = (unsigned short*)(ws + 67108864);    // 16 MiB
    unsigned short* h1   = (unsigned short*)(ws + 83886080);    // 16 MiB
    unsigned short* Wb0f = (unsigned short*)(ws + 67108864);    // 1024x320 bf16
    unsigned short* Wb0b = (unsigned short*)(ws + 67764224);
    unsigned short* Abf  = (unsigned short*)(ws + 83886080);    // 16384x320 bf16 (10 MiB)
    unsigned short* Wb1f = (unsigned short*)(ws + 94371840);    // 1024x512 bf16
    unsigned short* Wb1b = (unsigned short*)(ws + 95420416);
    unsigned int*   WP   = (unsigned int*)(ws + 100663296);     // 4 x 512 KiB
    float*        WsbjT  = (float*)(ws + 102760448);            // 76 KiB
    float*          acc  = (float*)(ws + 102836224);            // 8 B
    float*           em  = (float*)(ws + 0);                    // 2.4 MiB (over zf)
    float* out = (float*)d_out;

    unsigned int* WP0f = WP + 0 * 131072;
    unsigned int* WP0b = WP + 1 * 131072;
    unsigned int* WP1f = WP + 2 * 131072;
    unsigned int* WP1b = WP + 3 * 131072;

    init_kernel<<<1, 64, 0, stream>>>(acc);
    conv_whh<<<dim3(2048), 256, 0, stream>>>(Whh0f, Whh0b, Whh1f, Whh1b, WP);
    conv_wsbj<<<dim3(74), 256, 0, stream>>>(Wsbj, WsbjT);
    conv_gather<<<dim3(MTOT), 320, 0, stream>>>(text, emb, Abf);
    conv_w<<<dim3(1280), 256, 0, stream>>>(Wih0f, Wb0f, DD, KP0, 1024 * KP0);
    conv_w<<<dim3(1280), 256, 0, stream>>>(Wih0b, Wb0b, DD, KP0, 1024 * KP0);
    conv_w<<<dim3(2048), 256, 0, stream>>>(Wih1f, Wb1f, 512, 512, 1024 * 512);
    conv_w<<<dim3(2048), 256, 0, stream>>>(Wih1b, Wb1b, 512, 512, 1024 * 512);

    // layer 0 input projection (MFMA)
    gemm_mfma<<<dim3(128, 8), 256, 0, stream>>>(Abf, Wb0f, b0f, zf, KP0);
    gemm_mfma<<<dim3(128, 8), 256, 0, stream>>>(Abf, Wb0b, b0b, zb, KP0);
    lstm_kernel<<<dim3(BB, 2), 1024, 0, stream>>>(zf, zb, WP0f, WP0b, h0);
    // layer 1 input projection (MFMA)
    gemm_mfma<<<dim3(128, 8), 256, 0, stream>>>(h0, Wb1f, b1f, zf, 512);
    gemm_mfma<<<dim3(128, 8), 256, 0, stream>>>(h0, Wb1b, b1b, zb, 512);
    lstm_kernel<<<dim3(BB, 2), 1024, 0, stream>>>(zf, zb, WP1f, WP1b, h1);

    em_kernel<<<(MTOT * KK + 255) / 256, 256, 0, stream>>>(h1, WsbjT, bsbj, em);
    crf_kernel<<<BB, 64, 0, stream>>>(text, sbj, em, start_t, end_t, trans, acc);
    final_kernel<<<1, 1, 0, stream>>>(acc, out);
}

// Round 6
// 3048.355 us; speedup vs baseline: 4.2197x; 4.2197x over previous
//
#include <hip/hip_runtime.h>
#include <math.h>

// Problem constants
#define TT 256      // sequence length
#define BB 64       // batch
#define DD 300      // embedding dim
#define KP0 320     // layer-0 K padded to multiple of 32
#define HH 256      // hidden
#define KK 37       // CRF states
#define FH 1024     // 4*H
#define MTOT (TT*BB) // 16384 rows, time-major r = t*64 + b

typedef __attribute__((ext_vector_type(8))) short short8;  // 8 bf16 (4 VGPR) MFMA A/B frag
typedef __attribute__((ext_vector_type(4))) float f32x4;   // MFMA C/D frag

// ---------- bf16 helpers ----------
__device__ __forceinline__ float bf2f(unsigned short u) {
    union { float f; unsigned int i; } v; v.i = ((unsigned int)u) << 16; return v.f;
}
__device__ __forceinline__ unsigned short f2bf(float f) {
    union { float f; unsigned int i; } v; v.f = f;
    unsigned int i = v.i;
    unsigned int r = (i + 0x7FFFu + ((i >> 16) & 1u)) >> 16; // RNE
    return (unsigned short)r;
}
__device__ __forceinline__ float bflo(unsigned int w) {
    union { float f; unsigned int i; } v; v.i = w << 16; return v.f;
}
__device__ __forceinline__ float bfhi(unsigned int w) {
    union { float f; unsigned int i; } v; v.i = w & 0xFFFF0000u; return v.f;
}
__device__ __forceinline__ float sigm(float x)   { return 1.0f / (1.0f + __expf(-x)); }
__device__ __forceinline__ float tanh_f(float x) { return 2.0f / (1.0f + __expf(-2.0f * x)) - 1.0f; }

// permute gate-major col (g*256+unit) -> interleaved (unit*4+g)
__device__ __forceinline__ int perm_col(int nn) { return ((nn & 255) << 2) | (nn >> 8); }

// ---------- prep: WP packed bf16 recurrent weights ----------
// word[((kq*32 + j2)*256 + u)*4 + w4], k = kq*64 + j2*2 + (w4>>1)
// w4&1==0 -> pack(gate_i, gate_f) at k ; w4&1==1 -> pack(gate_g, gate_o)
__global__ __launch_bounds__(256) void conv_whh(
    const float* __restrict__ w0f, const float* __restrict__ w0b,
    const float* __restrict__ w1f, const float* __restrict__ w1b,
    unsigned int* __restrict__ WP)
{
    const int idx = blockIdx.x * 256 + threadIdx.x;
    const int m = idx >> 17;
    const int r = idx & 131071;
    const float* W = m == 0 ? w0f : m == 1 ? w0b : m == 2 ? w1f : w1b;
    const int w4 = r & 3;
    const int u  = (r >> 2) & 255;
    const int j2 = (r >> 10) & 31;
    const int kq = r >> 15;
    const int k  = kq * 64 + j2 * 2 + (w4 >> 1);
    const int g01 = w4 & 1;
    const float f0 = W[((g01 * 2 + 0) * HH + u) * HH + k];
    const float f1 = W[((g01 * 2 + 1) * HH + u) * HH + k];
    WP[idx] = (unsigned int)f2bf(f0) | ((unsigned int)f2bf(f1) << 16);
}

// ---------- prep: WsbjT f32 [512][37] ----------
__global__ __launch_bounds__(256) void conv_wsbj(
    const float* __restrict__ Wsbj, float* __restrict__ WT)
{
    const int idx = blockIdx.x * 256 + threadIdx.x;
    if (idx >= 512 * KK) return;
    const int c = idx / KK, k = idx - c * KK;
    WT[idx] = Wsbj[k * 512 + c];
}

// ---------- prep: gather embedding rows -> Abf bf16 [16384][320] (zero-pad k>=300) ----------
__global__ __launch_bounds__(320) void conv_gather(
    const int* __restrict__ text, const float* __restrict__ emb,
    unsigned short* __restrict__ Abf)
{
    const int r = blockIdx.x;
    const int k = threadIdx.x;
    const int t = r >> 6, b = r & 63;
    const int idx = text[b * TT + t];
    Abf[r * KP0 + k] = (k < DD) ? f2bf(emb[(size_t)idx * DD + k]) : (unsigned short)0;
}

// ---------- prep: W f32 (rows x kin) -> bf16 (rows x kout), zero-pad ----------
__global__ __launch_bounds__(256) void conv_w(
    const float* __restrict__ src, unsigned short* __restrict__ dst,
    int kin, int kout, int total)
{
    const int idx = blockIdx.x * 256 + threadIdx.x;
    if (idx >= total) return;
    const int rr = idx / kout, k = idx - rr * kout;
    dst[idx] = (k < kin) ? f2bf(src[rr * kin + k]) : (unsigned short)0;
}

// ---------- MFMA GEMM: out = A(M x lda bf16) @ W(1024 x lda bf16)^T + bias ----------
// 128x128 tile, 256 threads (4 waves, each 64x64 = 4x4 MFMA_16x16x32_bf16).
// Staging via global_load_lds width=16 (linear LDS layout = lane order, no padding).
// Epilogue: bias add + bf16 + gate-interleave permute store.
__global__ __launch_bounds__(256) void gemm_mfma(
    const unsigned short* __restrict__ A,
    const unsigned short* __restrict__ W,
    const float* __restrict__ bias,
    unsigned short* __restrict__ out,
    int lda)
{
    const int bm = blockIdx.x * 128;
    const int bn = blockIdx.y * 128;
    const int tid = threadIdx.x;
    const int lane = tid & 63;
    const int wave = tid >> 6;
    const int wm = (wave & 1) * 64;
    const int wn = (wave >> 1) * 64;

    __shared__ __align__(16) unsigned short As[128 * 32];  // [row][k] 8 KB
    __shared__ __align__(16) unsigned short Bs[128 * 32];  // [wrow][k] 8 KB

    f32x4 acc[4][4] = {};

    const int srow = tid >> 2;          // 0..63
    const int sk = (tid & 3) * 8;       // k element offset (16 B granules)

    const unsigned short* ga0 = A + (size_t)(bm + srow) * lda + sk;
    const unsigned short* ga1 = A + (size_t)(bm + srow + 64) * lda + sk;
    const unsigned short* gb0 = W + (size_t)(bn + srow) * lda + sk;
    const unsigned short* gb1 = W + (size_t)(bn + srow + 64) * lda + sk;

    unsigned short* lA0 = As + wave * 512;           // byte off = wave*1024 (+lane*16 by HW)
    unsigned short* lA1 = As + 2048 + wave * 512;
    unsigned short* lB0 = Bs + wave * 512;
    unsigned short* lB1 = Bs + 2048 + wave * 512;

    const int kiters = lda >> 5;
    for (int kb = 0; kb < kiters; kb++) {
        const int k0 = kb * 32;
        __builtin_amdgcn_global_load_lds(
            (const __attribute__((address_space(1))) unsigned int*)(ga0 + k0),
            (__attribute__((address_space(3))) unsigned int*)lA0, 16, 0, 0);
        __builtin_amdgcn_global_load_lds(
            (const __attribute__((address_space(1))) unsigned int*)(ga1 + k0),
            (__attribute__((address_space(3))) unsigned int*)lA1, 16, 0, 0);
        __builtin_amdgcn_global_load_lds(
            (const __attribute__((address_space(1))) unsigned int*)(gb0 + k0),
            (__attribute__((address_space(3))) unsigned int*)lB0, 16, 0, 0);
        __builtin_amdgcn_global_load_lds(
            (const __attribute__((address_space(1))) unsigned int*)(gb1 + k0),
            (__attribute__((address_space(3))) unsigned int*)lB1, 16, 0, 0);
        __syncthreads();

        short8 af[4], bfr[4];
        #pragma unroll
        for (int i = 0; i < 4; i++) {
            af[i]  = *(const short8*)&As[(wm + i * 16 + (lane & 15)) * 32 + (lane >> 4) * 8];
            bfr[i] = *(const short8*)&Bs[(wn + i * 16 + (lane & 15)) * 32 + (lane >> 4) * 8];
        }
        #pragma unroll
        for (int i = 0; i < 4; i++)
            #pragma unroll
            for (int j = 0; j < 4; j++)
                acc[i][j] = __builtin_amdgcn_mfma_f32_16x16x32_bf16(af[i], bfr[j], acc[i][j], 0, 0, 0);
        __syncthreads();
    }

    // C/D: col = lane&15, row = (lane>>4)*4 + reg  [measured m89/m91]
    const int cn = lane & 15;
    const int cr = (lane >> 4) * 4;
    #pragma unroll
    for (int j = 0; j < 4; j++) {
        const int n = bn + wn + j * 16 + cn;
        const float bv = bias[n];
        const int pc = perm_col(n);
        #pragma unroll
        for (int i = 0; i < 4; i++) {
            #pragma unroll
            for (int r = 0; r < 4; r++) {
                const int m = bm + wm + i * 16 + cr + r;
                out[(size_t)m * FH + pc] = f2bf(acc[i][j][r] + bv);
            }
        }
    }
}

// ---------- LSTM recurrence: grid (64 batches, 2 dirs), 1024 threads ----------
// tid = kq*256 + u : thread accumulates 4 gates of unit u over k in [kq*64, kq*64+64).
// kq is wave-uniform -> LDS h reads are pure broadcast (conflict-free).
// Weights streamed as coalesced uint4. NOTE: round-5's one-iteration-ahead
// software prefetch EXPLODED L2 misses (FETCH 37MB -> 10.2GB, 1.29ms -> 6.1ms).
// Keep this exact round-4 load schedule; do not re-introduce manual prefetch.
__global__ __launch_bounds__(1024) void lstm_kernel(
    const unsigned short* __restrict__ zin_f, const unsigned short* __restrict__ zin_b,
    const unsigned int* __restrict__ WPf, const unsigned int* __restrict__ WPb,
    unsigned short* __restrict__ h_out)  // (T,B,512) bf16; fwd cols [0:256), bwd [256:512)
{
    const int dir = blockIdx.y;
    const unsigned short* zin = dir ? zin_b : zin_f;
    const unsigned int*   WP  = dir ? WPb : WPf;
    const int off = dir ? HH : 0;

    const int b = blockIdx.x;
    const int tid = threadIdx.x;
    const int u  = tid & 255;
    const int kq = tid >> 8;            // wave-uniform (waves 0-3:0, 4-7:1, ...)

    __shared__ float hs[2][HH];
    __shared__ float4 red[3][HH];
    if (tid < HH) hs[0][tid] = 0.0f;
    float c = 0.0f;
    int cur = 0;

    // uint4 stream base: uint4 index ((kq*32 + j2)*256 + u)
    const uint4* wp = (const uint4*)WP + (kq * 32) * 256 + u;

    __syncthreads();

    for (int ts = 0; ts < TT; ts++) {
        const int tt = dir ? (TT - 1 - ts) : ts;
        const int row = tt * BB + b;

        float ai = 0.f, af = 0.f, ag = 0.f, ao = 0.f;
        #pragma unroll 4
        for (int j4 = 0; j4 < 16; j4++) {
            const float4 hv = *(const float4*)&hs[cur][kq * 64 + j4 * 4];  // broadcast
            const uint4 wa = wp[(2 * j4 + 0) * 256];   // k+0,k+1
            const uint4 wb = wp[(2 * j4 + 1) * 256];   // k+2,k+3
            ai += bflo(wa.x) * hv.x; af += bfhi(wa.x) * hv.x;
            ag += bflo(wa.y) * hv.x; ao += bfhi(wa.y) * hv.x;
            ai += bflo(wa.z) * hv.y; af += bfhi(wa.z) * hv.y;
            ag += bflo(wa.w) * hv.y; ao += bfhi(wa.w) * hv.y;
            ai += bflo(wb.x) * hv.z; af += bfhi(wb.x) * hv.z;
            ag += bflo(wb.y) * hv.z; ao += bfhi(wb.y) * hv.z;
            ai += bflo(wb.z) * hv.w; af += bfhi(wb.z) * hv.w;
            ag += bflo(wb.w) * hv.w; ao += bfhi(wb.w) * hv.w;
        }

        if (kq) red[kq - 1][u] = make_float4(ai, af, ag, ao);
        __syncthreads();

        if (kq == 0) {
            const float4 r0 = red[0][u], r1 = red[1][u], r2 = red[2][u];
            const ushort4 zv = *(const ushort4*)(zin + row * FH + 4 * u);
            const float zi  = ai + r0.x + r1.x + r2.x + bf2f(zv.x);
            const float zf_ = af + r0.y + r1.y + r2.y + bf2f(zv.y);
            const float zg  = ag + r0.z + r1.z + r2.z + bf2f(zv.z);
            const float zo  = ao + r0.w + r1.w + r2.w + bf2f(zv.w);
            const float cc = sigm(zf_) * c + sigm(zi) * tanh_f(zg);
            c = cc;
            const float hh = sigm(zo) * tanh_f(cc);
            hs[cur ^ 1][u] = hh;
            h_out[row * (2 * HH) + off + u] = f2bf(hh);
        }
        __syncthreads();
        cur ^= 1;
    }
}

// ---------- Emission: em = h1 @ WsbjT + b_sbj, (MTOT,37) f32 ----------
__global__ __launch_bounds__(256) void em_kernel(
    const unsigned short* __restrict__ h1, const float* __restrict__ WsbjT,
    const float* __restrict__ bsbj, float* __restrict__ em)
{
    const int o = blockIdx.x * 256 + threadIdx.x;
    if (o >= MTOT * KK) return;
    const int r = o / KK, k = o - r * KK;
    const unsigned short* hr = h1 + r * 512;
    float s = bsbj[k];
    #pragma unroll 4
    for (int cidx = 0; cidx < 512; cidx++) {
        s += bf2f(hr[cidx]) * WsbjT[cidx * KK + k];
    }
    em[o] = s;
}

// ---------- CRF: one block (1 wave) per batch ----------
__global__ __launch_bounds__(64) void crf_kernel(
    const int* __restrict__ text, const int* __restrict__ sbj,
    const float* __restrict__ em,
    const float* __restrict__ start_t, const float* __restrict__ end_t,
    const float* __restrict__ trans, float* __restrict__ accum)
{
    const int b = blockIdx.x;
    const int tid = threadIdx.x;
    __shared__ float tr[KK * KK];
    __shared__ float sc[2][KK];
    for (int x = tid; x < KK * KK; x += 64) tr[x] = trans[x];

    int cnt = 0;
    for (int t = tid; t < TT; t += 64) cnt += (text[b * TT + t] != 0) ? 1 : 0;
    #pragma unroll
    for (int s = 32; s > 0; s >>= 1) cnt += __shfl_down(cnt, s, 64);
    const int len = __shfl(cnt, 0, 64);

    __syncthreads();

    float part = 0.f;
    for (int t = tid; t < TT; t += 64) {
        if (t >= 1 && t < len) {
            const int tg = sbj[b * TT + t];
            const int tp = sbj[b * TT + t - 1];
            part += em[(t * BB + b) * KK + tg] + tr[tp * KK + tg];
        }
    }
    #pragma unroll
    for (int s = 32; s > 0; s >>= 1) part += __shfl_down(part, s, 64);

    if (tid < KK) sc[0][tid] = start_t[tid] + em[b * KK + tid];
    __syncthreads();
    int cur = 0;
    for (int t = 1; t < len; t++) {
        float nv = 0.f;
        if (tid < KK) {
            float mx = -1e30f;
            for (int k1 = 0; k1 < KK; k1++)
                mx = fmaxf(mx, sc[cur][k1] + tr[k1 * KK + tid]);
            float s = 0.f;
            for (int k1 = 0; k1 < KK; k1++)
                s += __expf(sc[cur][k1] + tr[k1 * KK + tid] - mx);
            nv = mx + __logf(s) + em[(t * BB + b) * KK + tid];
        }
        if (tid < KK) sc[cur ^ 1][tid] = nv;
        __syncthreads();
        cur ^= 1;
    }

    if (tid == 0) {
        const int tg0 = sbj[b * TT];
        const int tgl = sbj[b * TT + len - 1];
        const float num = start_t[tg0] + em[b * KK + tg0] + part + end_t[tgl];
        float mx = -1e30f;
        for (int k = 0; k < KK; k++) mx = fmaxf(mx, sc[cur][k] + end_t[k]);
        float s = 0.f;
        for (int k = 0; k < KK; k++) s += __expf(sc[cur][k] + end_t[k] - mx);
        const float logZ = mx + __logf(s);
        atomicAdd(&accum[0], num - logZ);
        atomicAdd(&accum[1], (float)len);
    }
}

__global__ void init_kernel(float* __restrict__ accum) {
    if (threadIdx.x < 2) accum[threadIdx.x] = 0.0f;
}
__global__ void final_kernel(const float* __restrict__ accum, float* __restrict__ out) {
    out[0] = -(accum[0] / accum[1]);
}

// ---------- launch ----------
extern "C" void kernel_launch(void* const* d_in, const int* in_sizes, int n_in,
                              void* d_out, int out_size, void* d_ws, size_t ws_size,
                              hipStream_t stream)
{
    (void)in_sizes; (void)n_in; (void)out_size; (void)ws_size;
    const int*   text  = (const int*)d_in[0];
    const int*   sbj   = (const int*)d_in[1];
    const float* emb   = (const float*)d_in[2];
    const float* Wih0f = (const float*)d_in[3];
    const float* Whh0f = (const float*)d_in[4];
    const float* b0f   = (const float*)d_in[5];
    const float* Wih0b = (const float*)d_in[6];
    const float* Whh0b = (const float*)d_in[7];
    const float* b0b   = (const float*)d_in[8];
    const float* Wih1f = (const float*)d_in[9];
    const float* Whh1f = (const float*)d_in[10];
    const float* b1f   = (const float*)d_in[11];
    const float* Wih1b = (const float*)d_in[12];
    const float* Whh1b = (const float*)d_in[13];
    const float* b1b   = (const float*)d_in[14];
    const float* Wsbj  = (const float*)d_in[15];
    const float* bsbj  = (const float*)d_in[16];
    const float* start_t = (const float*)d_in[17];
    const float* end_t   = (const float*)d_in[18];
    const float* trans   = (const float*)d_in[19];

    // workspace map (bytes), max 102.84 MB. Overlaps (stream-ordered lifetimes):
    //   Wb0f/Wb0b live in h0 region  (dead before lstm0 writes h0)
    //   Abf, Wb1f/Wb1b live in h1 region (dead before lstm1 writes h1)
    //   em reuses zf (dead after lstm1)
    char* ws = (char*)d_ws;
    unsigned short* zf   = (unsigned short*)(ws + 0);           // 32 MiB
    unsigned short* zb   = (unsigned short*)(ws + 33554432);    // 32 MiB
    unsigned short* h0   = (unsigned short*)(ws + 67108864);    // 16 MiB
    unsigned short* h1   = (unsigned short*)(ws + 83886080);    // 16 MiB
    unsigned short* Wb0f = (unsigned short*)(ws + 67108864);    // 1024x320 bf16
    unsigned short* Wb0b = (unsigned short*)(ws + 67764224);
    unsigned short* Abf  = (unsigned short*)(ws + 83886080);    // 16384x320 bf16 (10 MiB)
    unsigned short* Wb1f = (unsigned short*)(ws + 94371840);    // 1024x512 bf16
    unsigned short* Wb1b = (unsigned short*)(ws + 95420416);
    unsigned int*   WP   = (unsigned int*)(ws + 100663296);     // 4 x 512 KiB
    float*        WsbjT  = (float*)(ws + 102760448);            // 76 KiB
    float*          acc  = (float*)(ws + 102836224);            // 8 B
    float*           em  = (float*)(ws + 0);                    // 2.4 MiB (over zf)
    float* out = (float*)d_out;

    unsigned int* WP0f = WP + 0 * 131072;
    unsigned int* WP0b = WP + 1 * 131072;
    unsigned int* WP1f = WP + 2 * 131072;
    unsigned int* WP1b = WP + 3 * 131072;

    init_kernel<<<1, 64, 0, stream>>>(acc);
    conv_whh<<<dim3(2048), 256, 0, stream>>>(Whh0f, Whh0b, Whh1f, Whh1b, WP);
    conv_wsbj<<<dim3(74), 256, 0, stream>>>(Wsbj, WsbjT);
    conv_gather<<<dim3(MTOT), 320, 0, stream>>>(text, emb, Abf);
    conv_w<<<dim3(1280), 256, 0, stream>>>(Wih0f, Wb0f, DD, KP0, 1024 * KP0);
    conv_w<<<dim3(1280), 256, 0, stream>>>(Wih0b, Wb0b, DD, KP0, 1024 * KP0);
    conv_w<<<dim3(2048), 256, 0, stream>>>(Wih1f, Wb1f, 512, 512, 1024 * 512);
    conv_w<<<dim3(2048), 256, 0, stream>>>(Wih1b, Wb1b, 512, 512, 1024 * 512);

    // layer 0 input projection (MFMA)
    gemm_mfma<<<dim3(128, 8), 256, 0, stream>>>(Abf, Wb0f, b0f, zf, KP0);
    gemm_mfma<<<dim3(128, 8), 256, 0, stream>>>(Abf, Wb0b, b0b, zb, KP0);
    lstm_kernel<<<dim3(BB, 2), 1024, 0, stream>>>(zf, zb, WP0f, WP0b, h0);
    // layer 1 input projection (MFMA)
    gemm_mfma<<<dim3(128, 8), 256, 0, stream>>>(h0, Wb1f, b1f, zf, 512);
    gemm_mfma<<<dim3(128, 8), 256, 0, stream>>>(h0, Wb1b, b1b, zb, 512);
    lstm_kernel<<<dim3(BB, 2), 1024, 0, stream>>>(zf, zb, WP1f, WP1b, h1);

    em_kernel<<<(MTOT * KK + 255) / 256, 256, 0, stream>>>(h1, WsbjT, bsbj, em);
    crf_kernel<<<BB, 64, 0, stream>>>(text, sbj, em, start_t, end_t, trans, acc);
    final_kernel<<<1, 1, 0, stream>>>(acc, out);
}